// Round 1
// baseline (109.094 us; speedup 1.0000x reference)
//
#include <hip/hip_runtime.h>
#include <math.h>

#define NB     32      // blocks per batch
#define WAVES  4
#define NTHR   256
#define HDIM   1024

// Pass 1: online-softmax fused scores + weighted accumulation.
// Each block handles S/NB rows of one batch; each wave handles a contiguous
// chunk of rows, maintaining running (m, l, c[H]) distributed across lanes
// (16 elements per lane). Block-combines 4 wave partials via LDS, writes one
// partial (m, l, c[H]) per block to workspace.
__global__ __launch_bounds__(NTHR) void attn_pass1(
    const float* __restrict__ hidden,   // [B][H]
    const float* __restrict__ enc,      // [B][S][H]
    float* __restrict__ ws_c,           // [B*NB][H]
    float* __restrict__ ws_m,           // [B*NB]
    float* __restrict__ ws_l,           // [B*NB]
    int S)
{
    const int tid  = threadIdx.x;
    const int lane = tid & 63;
    const int w    = tid >> 6;
    const int b    = blockIdx.x / NB;
    const int blk  = blockIdx.x % NB;
    const int rowsPerBlock = S / NB;               // 128
    const int rowsPerWave  = rowsPerBlock / WAVES; // 32
    const int s_base = blk * rowsPerBlock + w * rowsPerWave;

    // hidden[b] fragment: lane owns h = q*256 + 4*lane + comp, q=0..3
    const float4* h4 = reinterpret_cast<const float4*>(hidden + (size_t)b * HDIM);
    float4 hreg[4];
    #pragma unroll
    for (int q = 0; q < 4; ++q) hreg[q] = h4[q * 64 + lane];

    float c[16];
    #pragma unroll
    for (int k = 0; k < 16; ++k) c[k] = 0.f;
    float m = -INFINITY, lsum = 0.f;

    for (int i = 0; i < rowsPerWave; ++i) {
        const int s = s_base + i;
        const float4* row4 =
            reinterpret_cast<const float4*>(enc + ((size_t)b * S + s) * HDIM);
        float4 e[4];
        float part = 0.f;
        #pragma unroll
        for (int q = 0; q < 4; ++q) {
            e[q] = row4[q * 64 + lane];
            part += e[q].x * hreg[q].x + e[q].y * hreg[q].y
                  + e[q].z * hreg[q].z + e[q].w * hreg[q].w;
        }
        // wave-64 butterfly reduce -> score uniform across lanes
        #pragma unroll
        for (int off = 32; off >= 1; off >>= 1)
            part += __shfl_xor(part, off);
        const float score = part;

        const float newm  = fmaxf(m, score);
        const float scale = __expf(m - newm);      // exp(-inf)=0 on first iter
        const float p     = __expf(score - newm);
        lsum = lsum * scale + p;
        const float* ef = reinterpret_cast<const float*>(e);
        #pragma unroll
        for (int k = 0; k < 16; ++k)
            c[k] = c[k] * scale + p * ef[k];
        m = newm;
    }

    // ---- block combine of 4 wave partials ----
    __shared__ float lds_c[WAVES][HDIM];   // 16 KB
    __shared__ float lds_m[WAVES];
    __shared__ float lds_l[WAVES];

    if (lane == 0) lds_m[w] = m;
    __syncthreads();
    const float M = fmaxf(fmaxf(lds_m[0], lds_m[1]), fmaxf(lds_m[2], lds_m[3]));
    const float f = __expf(m - M);
    if (lane == 0) lds_l[w] = lsum * f;
    #pragma unroll
    for (int q = 0; q < 4; ++q) {
        #pragma unroll
        for (int comp = 0; comp < 4; ++comp)
            lds_c[w][q * 256 + 4 * lane + comp] = c[q * 4 + comp] * f;
    }
    __syncthreads();

    const int pidx = b * NB + blk;
    // each thread sums 4 consecutive h positions over the 4 waves
    float4 sum;
    {
        const int h = tid * 4;
        sum.x = lds_c[0][h+0] + lds_c[1][h+0] + lds_c[2][h+0] + lds_c[3][h+0];
        sum.y = lds_c[0][h+1] + lds_c[1][h+1] + lds_c[2][h+1] + lds_c[3][h+1];
        sum.z = lds_c[0][h+2] + lds_c[1][h+2] + lds_c[2][h+2] + lds_c[3][h+2];
        sum.w = lds_c[0][h+3] + lds_c[1][h+3] + lds_c[2][h+3] + lds_c[3][h+3];
    }
    reinterpret_cast<float4*>(ws_c)[(size_t)pidx * (HDIM / 4) + tid] = sum;
    if (tid == 0) {
        ws_m[pidx] = M;
        ws_l[pidx] = lds_l[0] + lds_l[1] + lds_l[2] + lds_l[3];
    }
}

// Pass 2: merge NB partials per batch, normalize, write context[b][H].
__global__ __launch_bounds__(NTHR) void attn_pass2(
    const float* __restrict__ ws_c,
    const float* __restrict__ ws_m,
    const float* __restrict__ ws_l,
    float* __restrict__ out)
{
    const int b   = blockIdx.x;
    const int tid = threadIdx.x;

    float M = -INFINITY;
    #pragma unroll
    for (int j = 0; j < NB; ++j) M = fmaxf(M, ws_m[b * NB + j]);

    float L = 0.f;
    float4 acc = make_float4(0.f, 0.f, 0.f, 0.f);
    const float4* c4 = reinterpret_cast<const float4*>(ws_c);
    for (int j = 0; j < NB; ++j) {
        const float f = __expf(ws_m[b * NB + j] - M);
        L += ws_l[b * NB + j] * f;
        const float4 v = c4[(size_t)(b * NB + j) * (HDIM / 4) + tid];
        acc.x += v.x * f; acc.y += v.y * f; acc.z += v.z * f; acc.w += v.w * f;
    }
    const float inv = 1.f / L;
    float4 o = make_float4(acc.x * inv, acc.y * inv, acc.z * inv, acc.w * inv);
    reinterpret_cast<float4*>(out)[(size_t)b * (HDIM / 4) + tid] = o;
}

extern "C" void kernel_launch(void* const* d_in, const int* in_sizes, int n_in,
                              void* d_out, int out_size, void* d_ws, size_t ws_size,
                              hipStream_t stream) {
    const float* hidden = (const float*)d_in[0];
    const float* enc    = (const float*)d_in[1];
    float* out          = (float*)d_out;

    const int B = in_sizes[0] / HDIM;          // 32
    const int S = in_sizes[1] / in_sizes[0];   // 4096

    // workspace layout
    float* ws_c = (float*)d_ws;                          // B*NB*H floats (4 MB)
    float* ws_m = ws_c + (size_t)B * NB * HDIM;          // B*NB floats
    float* ws_l = ws_m + (size_t)B * NB;                 // B*NB floats

    attn_pass1<<<B * NB, NTHR, 0, stream>>>(hidden, enc, ws_c, ws_m, ws_l, S);
    attn_pass2<<<B, NTHR, 0, stream>>>(ws_c, ws_m, ws_l, out);
}

// Round 3
// 95.599 us; speedup vs baseline: 1.1412x; 1.1412x over previous
//
#include <hip/hip_runtime.h>
#include <math.h>

#define NB     32      // blocks per batch
#define WAVES  4
#define NTHR   256
#define HDIM   1024

typedef float floatv4 __attribute__((ext_vector_type(4)));

// Pass 1: online-softmax fused scores + weighted accumulation.
// Each block handles S/NB rows of one batch; each wave handles a contiguous
// chunk of rows, processing 2 rows per step with one-pair-ahead prefetch.
__global__ __launch_bounds__(NTHR, 4) void attn_pass1(
    const float* __restrict__ hidden,   // [B][H]
    const float* __restrict__ enc,      // [B][S][H]
    float* __restrict__ ws_c,           // [B*NB][H]
    float* __restrict__ ws_m,           // [B*NB]
    float* __restrict__ ws_l,           // [B*NB]
    int S)
{
    const int tid  = threadIdx.x;
    const int lane = tid & 63;
    const int w    = tid >> 6;
    const int b    = blockIdx.x / NB;
    const int blk  = blockIdx.x % NB;
    const int rowsPerBlock = S / NB;               // 128
    const int rowsPerWave  = rowsPerBlock / WAVES; // 32
    const int s_base = blk * rowsPerBlock + w * rowsPerWave;

    // hidden[b] fragment: lane owns h = q*256 + 4*lane + comp, q=0..3
    const floatv4* h4 = reinterpret_cast<const floatv4*>(hidden + (size_t)b * HDIM);
    floatv4 hreg[4];
    #pragma unroll
    for (int q = 0; q < 4; ++q) hreg[q] = h4[q * 64 + lane];

    float c[16];
    #pragma unroll
    for (int k = 0; k < 16; ++k) c[k] = 0.f;
    float m = -INFINITY, lsum = 0.f;

    // row pointers (float4 units); one row = 256 float4
    const floatv4* row = reinterpret_cast<const floatv4*>(
        enc + ((size_t)b * S + s_base) * HDIM) + lane;

    floatv4 e0[4], e1[4];
    #pragma unroll
    for (int q = 0; q < 4; ++q) {
        e0[q] = __builtin_nontemporal_load(&row[q * 64]);
        e1[q] = __builtin_nontemporal_load(&row[256 + q * 64]);
    }
    row += 512;

    for (int i = 0; i < rowsPerWave; i += 2) {
        floatv4 f0[4], f1[4];
        if (i + 2 < rowsPerWave) {
            #pragma unroll
            for (int q = 0; q < 4; ++q) {
                f0[q] = __builtin_nontemporal_load(&row[q * 64]);
                f1[q] = __builtin_nontemporal_load(&row[256 + q * 64]);
            }
            row += 512;
        }

        float p0 = 0.f, p1 = 0.f;
        #pragma unroll
        for (int q = 0; q < 4; ++q) {
            p0 += e0[q].x * hreg[q].x + e0[q].y * hreg[q].y
                + e0[q].z * hreg[q].z + e0[q].w * hreg[q].w;
            p1 += e1[q].x * hreg[q].x + e1[q].y * hreg[q].y
                + e1[q].z * hreg[q].z + e1[q].w * hreg[q].w;
        }
        // two independent wave-64 butterfly reductions, interleaved
        #pragma unroll
        for (int off = 32; off >= 1; off >>= 1) {
            p0 += __shfl_xor(p0, off);
            p1 += __shfl_xor(p1, off);
        }
        const float s0 = p0, s1 = p1;
        const float mx01 = fmaxf(s0, s1);
        const float* e0f = reinterpret_cast<const float*>(e0);
        const float* e1f = reinterpret_cast<const float*>(e1);

        if (mx01 <= m) {
            // common path after warm-up: running max unchanged, no rescale
            const float w0 = __expf(s0 - m);
            const float w1 = __expf(s1 - m);
            lsum += w0 + w1;
            #pragma unroll
            for (int k = 0; k < 16; ++k)
                c[k] += w0 * e0f[k] + w1 * e1f[k];
        } else {
            const float newm  = mx01;
            const float scale = __expf(m - newm);   // exp(-inf)=0 first iter
            const float w0 = __expf(s0 - newm);
            const float w1 = __expf(s1 - newm);
            lsum = lsum * scale + w0 + w1;
            #pragma unroll
            for (int k = 0; k < 16; ++k)
                c[k] = c[k] * scale + w0 * e0f[k] + w1 * e1f[k];
            m = newm;
        }

        #pragma unroll
        for (int q = 0; q < 4; ++q) { e0[q] = f0[q]; e1[q] = f1[q]; }
    }

    // ---- block combine of 4 wave partials ----
    __shared__ float lds_c[WAVES][HDIM];   // 16 KB
    __shared__ float lds_m[WAVES];
    __shared__ float lds_l[WAVES];

    if (lane == 0) lds_m[w] = m;
    __syncthreads();
    const float M = fmaxf(fmaxf(lds_m[0], lds_m[1]), fmaxf(lds_m[2], lds_m[3]));
    const float f = __expf(m - M);
    if (lane == 0) lds_l[w] = lsum * f;
    #pragma unroll
    for (int q = 0; q < 4; ++q) {
        #pragma unroll
        for (int comp = 0; comp < 4; ++comp)
            lds_c[w][q * 256 + 4 * lane + comp] = c[q * 4 + comp] * f;
    }
    __syncthreads();

    const int pidx = b * NB + blk;
    float4 sum;
    {
        const int h = tid * 4;
        sum.x = lds_c[0][h+0] + lds_c[1][h+0] + lds_c[2][h+0] + lds_c[3][h+0];
        sum.y = lds_c[0][h+1] + lds_c[1][h+1] + lds_c[2][h+1] + lds_c[3][h+1];
        sum.z = lds_c[0][h+2] + lds_c[1][h+2] + lds_c[2][h+2] + lds_c[3][h+2];
        sum.w = lds_c[0][h+3] + lds_c[1][h+3] + lds_c[2][h+3] + lds_c[3][h+3];
    }
    reinterpret_cast<float4*>(ws_c)[(size_t)pidx * (HDIM / 4) + tid] = sum;
    if (tid == 0) {
        ws_m[pidx] = M;
        ws_l[pidx] = lds_l[0] + lds_l[1] + lds_l[2] + lds_l[3];
    }
}

// Pass 2: merge NB partials per batch, normalize, write context[b][H].
// grid = B*4 blocks of 64 threads; each block handles 64 float4 of H.
__global__ __launch_bounds__(64) void attn_pass2(
    const float* __restrict__ ws_c,
    const float* __restrict__ ws_m,
    const float* __restrict__ ws_l,
    float* __restrict__ out)
{
    const int b    = blockIdx.x >> 2;
    const int quad = blockIdx.x & 3;
    const int tid  = threadIdx.x;
    const int v    = quad * 64 + tid;       // float4 index within H/4=256

    float M = -INFINITY;
    #pragma unroll
    for (int j = 0; j < NB; ++j) M = fmaxf(M, ws_m[b * NB + j]);

    float L = 0.f;
    float4 acc = make_float4(0.f, 0.f, 0.f, 0.f);
    const float4* c4 = reinterpret_cast<const float4*>(ws_c);
    for (int j = 0; j < NB; ++j) {
        const float f = __expf(ws_m[b * NB + j] - M);
        L += ws_l[b * NB + j] * f;
        const float4 x = c4[(size_t)(b * NB + j) * (HDIM / 4) + v];
        acc.x += x.x * f; acc.y += x.y * f; acc.z += x.z * f; acc.w += x.w * f;
    }
    const float inv = 1.f / L;
    float4 o = make_float4(acc.x * inv, acc.y * inv, acc.z * inv, acc.w * inv);
    reinterpret_cast<float4*>(out)[(size_t)b * (HDIM / 4) + v] = o;
}

extern "C" void kernel_launch(void* const* d_in, const int* in_sizes, int n_in,
                              void* d_out, int out_size, void* d_ws, size_t ws_size,
                              hipStream_t stream) {
    const float* hidden = (const float*)d_in[0];
    const float* enc    = (const float*)d_in[1];
    float* out          = (float*)d_out;

    const int B = in_sizes[0] / HDIM;          // 32
    const int S = in_sizes[1] / in_sizes[0];   // 4096

    float* ws_c = (float*)d_ws;                          // B*NB*H floats (4 MB)
    float* ws_m = ws_c + (size_t)B * NB * HDIM;          // B*NB floats
    float* ws_l = ws_m + (size_t)B * NB;                 // B*NB floats

    attn_pass1<<<B * NB, NTHR, 0, stream>>>(hidden, enc, ws_c, ws_m, ws_l, S);
    attn_pass2<<<B * 4, 64, 0, stream>>>(ws_c, ws_m, ws_l, out);
}